// Round 1
// baseline (319.536 us; speedup 1.0000x reference)
//
#include <hip/hip_runtime.h>
#include <hip/hip_bf16.h>

typedef __bf16 bf16_t;
typedef __bf16 bf16x8 __attribute__((ext_vector_type(8)));
typedef __bf16 bf16x4 __attribute__((ext_vector_type(4)));
typedef float  f32x4  __attribute__((ext_vector_type(4)));

#define D_MODEL   1024
#define NUM_HEADS 16
#define HEAD_DIM  64
#define SEQ       2048
#define BATCH     2
#define NTOK      (BATCH*SEQ)   // 4096

// XOR slot swizzle for LDS tiles with 128-byte rows: permutes the eight 16B
// slots of each row by (row&7) -> conflict-free ds_read_b128 column-slice reads.
__device__ __forceinline__ int swz128(int row, int bytecol) {
  return row*128 + ((((bytecol>>4) ^ (row&7))<<4) | (bytecol & 15));
}

// ---------------- fp32 -> bf16 conversion ----------------
__global__ void cvt_f32_bf16(const float* __restrict__ in, bf16_t* __restrict__ out, int n) {
  int i = (blockIdx.x*blockDim.x + threadIdx.x)*4;
  if (i >= n) return;
  float4 v = *reinterpret_cast<const float4*>(in + i);
  bf16x4 o;
  o[0] = (bf16_t)v.x; o[1] = (bf16_t)v.y; o[2] = (bf16_t)v.z; o[3] = (bf16_t)v.w;
  *reinterpret_cast<bf16x4*>(out + i) = o;
}

// ---------------- RoPE (in-place on bf16 Q or K) ----------------
// pair id i: j = i&31 (freq index), token t = i>>9, element base = 2*i.
__global__ void rope_kernel(bf16_t* __restrict__ X, const int* __restrict__ pos, int npairs) {
  int i = blockIdx.x*blockDim.x + threadIdx.x;
  if (i >= npairs) return;
  int j = i & 31;
  int t = i >> 9;                 // b*S + s
  int s = t & (SEQ-1);
  float p = (float)pos[s];
  // inv_freq = theta^(-j/32) = 2^(-j/32 * log2(10000))
  float freq = exp2f(-(float)j * (13.287712379549449f/32.0f));
  float ang = p * freq;
  float sv, cv;
  sincosf(ang, &sv, &cv);
  int base = i*2;
  float xe = (float)X[base];
  float xo = (float)X[base+1];
  X[base]   = (bf16_t)(xe*cv - xo*sv);
  X[base+1] = (bf16_t)(xe*sv + xo*cv);
}

// ---------------- GEMM: C[M,N] = A[M,K] * B[N,K]^T (both bf16, K-major) ----------------
// 128x128 tile, BK=64, 4 waves (2x2), each wave 64x64 = 4x4 mfma_16x16x32 frags.
template<typename OutT>
__global__ __launch_bounds__(256) void gemm_bt(const bf16_t* __restrict__ A,
                                               const bf16_t* __restrict__ B,
                                               OutT* __restrict__ C,
                                               int M, int N, int K) {
  __shared__ __align__(16) char lA[128*128];  // 128 rows x 64 bf16 (128B), swizzled
  __shared__ __align__(16) char lB[128*128];
  int tid = threadIdx.x;
  int n0 = blockIdx.x*128, m0 = blockIdx.y*128;
  int wid = tid>>6, lane = tid&63;
  int wr = wid>>1, wc = wid&1;
  int lr = lane&15, lg = lane>>4;

  f32x4 acc[4][4];
  #pragma unroll
  for (int a=0;a<4;a++)
    #pragma unroll
    for (int b=0;b<4;b++) acc[a][b] = (f32x4){0.f,0.f,0.f,0.f};

  for (int k0 = 0; k0 < K; k0 += 64) {
    __syncthreads();
    #pragma unroll
    for (int p=0;p<4;p++) {
      int idx = p*256 + tid;
      int r = idx>>3, c8 = (idx&7)*8;
      bf16x8 va = *reinterpret_cast<const bf16x8*>(A + (size_t)(m0+r)*K + k0 + c8);
      *reinterpret_cast<bf16x8*>(lA + swz128(r, c8*2)) = va;
      bf16x8 vb = *reinterpret_cast<const bf16x8*>(B + (size_t)(n0+r)*K + k0 + c8);
      *reinterpret_cast<bf16x8*>(lB + swz128(r, c8*2)) = vb;
    }
    __syncthreads();
    #pragma unroll
    for (int t=0;t<2;t++) {
      bf16x8 af[4], bfr[4];
      #pragma unroll
      for (int mi=0;mi<4;mi++) {
        int row = wr*64 + mi*16 + lr;
        af[mi] = *reinterpret_cast<const bf16x8*>(lA + swz128(row, t*64 + lg*16));
      }
      #pragma unroll
      for (int ni=0;ni<4;ni++) {
        int row = wc*64 + ni*16 + lr;
        bfr[ni] = *reinterpret_cast<const bf16x8*>(lB + swz128(row, t*64 + lg*16));
      }
      #pragma unroll
      for (int mi=0;mi<4;mi++)
        #pragma unroll
        for (int ni=0;ni<4;ni++)
          acc[mi][ni] = __builtin_amdgcn_mfma_f32_16x16x32_bf16(af[mi], bfr[ni], acc[mi][ni], 0, 0, 0);
    }
  }

  #pragma unroll
  for (int mi=0;mi<4;mi++)
    #pragma unroll
    for (int ni=0;ni<4;ni++)
      #pragma unroll
      for (int r=0;r<4;r++) {
        int m = m0 + wr*64 + mi*16 + lg*4 + r;
        int n = n0 + wc*64 + ni*16 + lr;
        C[(size_t)m*N + n] = (OutT)acc[mi][ni][r];
      }
}

// ---------------- Flash causal attention ----------------
// grid: (S/64, B*H). block: 256 (4 waves x 16 q-rows). KV tile = 64 keys.
__global__ __launch_bounds__(256) void attn_kernel(const bf16_t* __restrict__ Qf,
                                                   const bf16_t* __restrict__ Kf,
                                                   const bf16_t* __restrict__ Vf,
                                                   bf16_t* __restrict__ Of) {
  __shared__ __align__(16) char sK [64*128];     // [key][dim]  swizzled
  __shared__ __align__(16) char sVt[64*128];     // [dim][key]  swizzled (transposed V)
  __shared__ __align__(16) char sP [4][16*128];  // per-wave P [qrow][key] swizzled

  int tileQ = blockIdx.x;
  int bh    = blockIdx.y;
  int b = bh >> 4, h = bh & 15;
  int tid = threadIdx.x, wid = tid>>6, lane = tid&63;
  int lr = lane&15, lg = lane>>4;
  int q0 = tileQ*64 + wid*16;        // this wave's q base

  // Q fragments (16 rows x 64 dims = 2 k-steps), held in regs for all tiles
  bf16x8 qf[2];
  const bf16_t* qbase = Qf + ((size_t)(b*SEQ) + q0 + lr)*D_MODEL + h*HEAD_DIM;
  qf[0] = *reinterpret_cast<const bf16x8*>(qbase + 0  + lg*8);
  qf[1] = *reinterpret_cast<const bf16x8*>(qbase + 32 + lg*8);

  f32x4 Oacc[4];
  #pragma unroll
  for (int ni=0;ni<4;ni++) Oacc[ni] = (f32x4){0.f,0.f,0.f,0.f};
  float mrun[4], lrun[4];
  #pragma unroll
  for (int r=0;r<4;r++) { mrun[r] = -INFINITY; lrun[r] = 0.f; }
  const float scale = 0.125f;   // 1/sqrt(64)

  int nT = tileQ + 1;            // causal: keys 0 .. (tileQ*64+63)
  for (int ti = 0; ti < nT; ++ti) {
    int k0 = ti*64;
    __syncthreads();   // protect sK/sVt (and flush prior P reads)
    // stage K (row-major swizzled) and V transposed
    #pragma unroll
    for (int p=0;p<2;p++) {
      int idx = p*256 + tid;
      int key = idx>>3, d8 = (idx&7)*8;
      const size_t grow = ((size_t)(b*SEQ) + k0 + key)*D_MODEL + h*HEAD_DIM + d8;
      bf16x8 kv = *reinterpret_cast<const bf16x8*>(Kf + grow);
      *reinterpret_cast<bf16x8*>(sK + swz128(key, d8*2)) = kv;
      bf16x8 vv = *reinterpret_cast<const bf16x8*>(Vf + grow);
      #pragma unroll
      for (int e=0;e<8;e++)
        *reinterpret_cast<bf16_t*>(sVt + swz128(d8+e, key*2)) = vv[e];
    }
    __syncthreads();

    // S = Q K^T  (16 q x 64 keys per wave)
    f32x4 sfr[4];
    #pragma unroll
    for (int cb=0;cb<4;cb++) sfr[cb] = (f32x4){0.f,0.f,0.f,0.f};
    #pragma unroll
    for (int t=0;t<2;t++)
      #pragma unroll
      for (int cb=0;cb<4;cb++) {
        bf16x8 kfr = *reinterpret_cast<const bf16x8*>(sK + swz128(cb*16 + lr, t*64 + lg*16));
        sfr[cb] = __builtin_amdgcn_mfma_f32_16x16x32_bf16(qf[t], kfr, sfr[cb], 0, 0, 0);
      }

    // online softmax per q-row (rows r live in 16-lane groups)
    float pv[4][4];  // [r][cb]
    #pragma unroll
    for (int r=0;r<4;r++) {
      int qg = q0 + lg*4 + r;
      float rmax = -INFINITY;
      #pragma unroll
      for (int cb=0;cb<4;cb++) {
        int kg = k0 + cb*16 + lr;
        float sv = sfr[cb][r]*scale;
        sv = (kg <= qg) ? sv : -INFINITY;
        pv[r][cb] = sv;
        rmax = fmaxf(rmax, sv);
      }
      #pragma unroll
      for (int m=1;m<16;m<<=1) rmax = fmaxf(rmax, __shfl_xor(rmax, m, 64));
      float mnew  = fmaxf(mrun[r], rmax);
      float alpha = expf(mrun[r] - mnew);
      mrun[r] = mnew;
      float rsum = 0.f;
      #pragma unroll
      for (int cb=0;cb<4;cb++) {
        float e = expf(pv[r][cb] - mnew);   // exp(-inf)=0 handles mask
        pv[r][cb] = e;
        rsum += e;
      }
      #pragma unroll
      for (int m=1;m<16;m<<=1) rsum += __shfl_xor(rsum, m, 64);
      lrun[r] = lrun[r]*alpha + rsum;
      #pragma unroll
      for (int ni=0;ni<4;ni++) Oacc[ni][r] *= alpha;
      // write P row to per-wave LDS (bf16, swizzled)
      #pragma unroll
      for (int cb=0;cb<4;cb++) {
        int bc = (cb*16 + lr)*2;
        *reinterpret_cast<bf16_t*>(sP[wid] + swz128(lg*4 + r, bc)) = (bf16_t)pv[r][cb];
      }
    }
    // make this wave's P writes visible to its own lanes
    asm volatile("s_waitcnt lgkmcnt(0)" ::: "memory");
    __builtin_amdgcn_sched_barrier(0);

    // O += P V
    #pragma unroll
    for (int t=0;t<2;t++) {
      bf16x8 pf = *reinterpret_cast<const bf16x8*>(sP[wid] + swz128(lr, t*64 + lg*16));
      #pragma unroll
      for (int ni=0;ni<4;ni++) {
        bf16x8 vfr = *reinterpret_cast<const bf16x8*>(sVt + swz128(ni*16 + lr, t*64 + lg*16));
        Oacc[ni] = __builtin_amdgcn_mfma_f32_16x16x32_bf16(pf, vfr, Oacc[ni], 0, 0, 0);
      }
    }
  }

  // epilogue: O /= l, write bf16 (B,S,H*Dh)
  #pragma unroll
  for (int ni=0;ni<4;ni++)
    #pragma unroll
    for (int r=0;r<4;r++) {
      int q = q0 + lg*4 + r;
      float o = Oacc[ni][r] / lrun[r];
      Of[((size_t)(b*SEQ) + q)*D_MODEL + h*HEAD_DIM + ni*16 + lr] = (bf16_t)o;
    }
}

// ---------------- launch ----------------
extern "C" void kernel_launch(void* const* d_in, const int* in_sizes, int n_in,
                              void* d_out, int out_size, void* d_ws, size_t ws_size,
                              hipStream_t stream) {
  const float* x   = (const float*)d_in[0];
  const int*   pos = (const int*)  d_in[1];
  const float* wq  = (const float*)d_in[2];
  const float* wk  = (const float*)d_in[3];
  const float* wv  = (const float*)d_in[4];
  const float* wo  = (const float*)d_in[5];
  float* out = (float*)d_out;

  char* ws = (char*)d_ws;
  bf16_t* xb  = (bf16_t*)(ws);                 // 8 MB
  bf16_t* wqb = (bf16_t*)(ws + (8u<<20));      // 2 MB each
  bf16_t* wkb = (bf16_t*)(ws + (10u<<20));
  bf16_t* wvb = (bf16_t*)(ws + (12u<<20));
  bf16_t* wob = (bf16_t*)(ws + (14u<<20));
  bf16_t* Qf  = (bf16_t*)(ws + (16u<<20));     // 8 MB each
  bf16_t* Kf  = (bf16_t*)(ws + (24u<<20));
  bf16_t* Vf  = (bf16_t*)(ws + (32u<<20));
  bf16_t* Of  = (bf16_t*)(ws + (40u<<20));     // total 48 MB

  const int nx = NTOK*D_MODEL;      // 4,194,304
  const int nw = D_MODEL*D_MODEL;   // 1,048,576
  cvt_f32_bf16<<<nx/1024, 256, 0, stream>>>(x,  xb,  nx);
  cvt_f32_bf16<<<nw/1024, 256, 0, stream>>>(wq, wqb, nw);
  cvt_f32_bf16<<<nw/1024, 256, 0, stream>>>(wk, wkb, nw);
  cvt_f32_bf16<<<nw/1024, 256, 0, stream>>>(wv, wvb, nw);
  cvt_f32_bf16<<<nw/1024, 256, 0, stream>>>(wo, wob, nw);

  dim3 gproj(D_MODEL/128, NTOK/128);  // (8, 32)
  gemm_bt<bf16_t><<<gproj, 256, 0, stream>>>(xb, wqb, Qf, NTOK, D_MODEL, D_MODEL);
  gemm_bt<bf16_t><<<gproj, 256, 0, stream>>>(xb, wkb, Kf, NTOK, D_MODEL, D_MODEL);
  gemm_bt<bf16_t><<<gproj, 256, 0, stream>>>(xb, wvb, Vf, NTOK, D_MODEL, D_MODEL);

  const int npairs = NTOK*NUM_HEADS*32;   // 2,097,152
  rope_kernel<<<npairs/256, 256, 0, stream>>>(Qf, pos, npairs);
  rope_kernel<<<npairs/256, 256, 0, stream>>>(Kf, pos, npairs);

  dim3 gattn(SEQ/64, BATCH*NUM_HEADS);    // (32, 32)
  attn_kernel<<<gattn, 256, 0, stream>>>(Qf, Kf, Vf, Of);

  gemm_bt<float><<<gproj, 256, 0, stream>>>(Of, wob, out, NTOK, D_MODEL, D_MODEL);
}

// Round 2
// 206.814 us; speedup vs baseline: 1.5450x; 1.5450x over previous
//
#include <hip/hip_runtime.h>
#include <hip/hip_bf16.h>

typedef __bf16 bf16_t;
typedef __bf16 bf16x8 __attribute__((ext_vector_type(8)));
typedef __bf16 bf16x4 __attribute__((ext_vector_type(4)));
typedef float  f32x4  __attribute__((ext_vector_type(4)));
typedef unsigned int u32;

#define D_MODEL   1024
#define NQKV      3072
#define NUM_HEADS 16
#define HEAD_DIM  64
#define SEQ       2048
#define BATCH     2
#define NTOK      4096
// 0.125 * log2(e): folded into Q by rope so softmax uses exp2 directly
#define SM_SCALE_LOG2E 0.18033688011112042f

// XOR slot swizzle for LDS tiles with 128-byte rows: permutes the eight 16B
// slots of each row by (row&7) -> conflict-free ds_read_b128 column-slice reads.
__device__ __forceinline__ int swz128(int row, int bytecol) {
  return row*128 + ((((bytecol>>4) ^ (row&7))<<4) | (bytecol & 15));
}

// async global->LDS, 16 bytes per lane; LDS dest = wave-uniform base + lane*16
__device__ __forceinline__ void gload16(const void* g, void* l) {
  __builtin_amdgcn_global_load_lds((const __attribute__((address_space(1))) u32*)g,
                                   (__attribute__((address_space(3))) u32*)l, 16, 0, 0);
}

// ---------------- fp32 -> bf16 conversions ----------------
__global__ void cvt_x(const float* __restrict__ in, bf16_t* __restrict__ out) {
  int i = (blockIdx.x*256 + threadIdx.x)*4;
  float4 v = *reinterpret_cast<const float4*>(in + i);
  bf16x4 o; o[0]=(bf16_t)v.x; o[1]=(bf16_t)v.y; o[2]=(bf16_t)v.z; o[3]=(bf16_t)v.w;
  *reinterpret_cast<bf16x4*>(out + i) = o;
}

// wq|wk|wv -> wqkv[3072][1024] (row concat), wo -> wob
__global__ void cvt_w(const float* __restrict__ wq, const float* __restrict__ wk,
                      const float* __restrict__ wv, const float* __restrict__ wo,
                      bf16_t* __restrict__ wqkv, bf16_t* __restrict__ wob) {
  const int NW = D_MODEL*D_MODEL;
  int i = (blockIdx.x*256 + threadIdx.x)*4;
  float4 v;
  if      (i <   NW) v = *reinterpret_cast<const float4*>(wq + i);
  else if (i < 2*NW) v = *reinterpret_cast<const float4*>(wk + i - NW);
  else if (i < 3*NW) v = *reinterpret_cast<const float4*>(wv + i - 2*NW);
  else               v = *reinterpret_cast<const float4*>(wo + i - 3*NW);
  bf16x4 o; o[0]=(bf16_t)v.x; o[1]=(bf16_t)v.y; o[2]=(bf16_t)v.z; o[3]=(bf16_t)v.w;
  bf16_t* dst = (i < 3*NW) ? (wqkv + i) : (wob + i - 3*NW);
  *reinterpret_cast<bf16x4*>(dst) = o;
}

// ---------------- RoPE on Q and K inside QKV buffer (stride 3072) ----------------
// thread = one (token, head, freq-pair); Q gets the softmax scale folded in.
__global__ void rope_qk(bf16_t* __restrict__ QKV, const int* __restrict__ pos) {
  int i = blockIdx.x*256 + threadIdx.x;   // 0 .. 2M-1
  int j = i & 31;                          // freq index
  int hp = (i >> 5) & 15;                  // head
  int t  = i >> 9;                         // token 0..4095
  float ang = (float)pos[t & (SEQ-1)] * exp2f(-(float)j * (13.287712379549449f/32.0f));
  float sv, cv; sincosf(ang, &sv, &cv);
  size_t base = (size_t)t*NQKV + hp*64 + 2*j;
  float xe = (float)QKV[base], xo = (float)QKV[base+1];
  QKV[base]   = (bf16_t)((xe*cv - xo*sv)*SM_SCALE_LOG2E);
  QKV[base+1] = (bf16_t)((xe*sv + xo*cv)*SM_SCALE_LOG2E);
  xe = (float)QKV[base+1024]; xo = (float)QKV[base+1025];
  QKV[base+1024] = (bf16_t)(xe*cv - xo*sv);
  QKV[base+1025] = (bf16_t)(xe*sv + xo*cv);
}

// ---------------- GEMM: C[M,N] = A[M,K] * B[N,K]^T (m97-style staging) --------
// 128x128 tile, BK=64, linear LDS + global_load_lds(16B). If QKV: column block
// n>=2048 (the V projection) is written TRANSPOSED to Vt[(b*16+h)*64+d][s].
template<typename OutT, bool QKV>
__global__ __launch_bounds__(256) void gemm_bt(const bf16_t* __restrict__ A,
                                               const bf16_t* __restrict__ B,
                                               OutT* __restrict__ C,
                                               bf16_t* __restrict__ Vt,
                                               int M, int N, int K) {
  __shared__ __align__(16) char lA[128*128];  // [128 rows][64 bf16] linear
  __shared__ __align__(16) char lB[128*128];
  int tid = threadIdx.x;
  int n0 = blockIdx.x*128, m0 = blockIdx.y*128;
  int wid = tid>>6, lane = tid&63;
  int wr = wid>>1, wc = wid&1;
  int lr = lane&15, lg = lane>>4;

  const bf16_t* ga = A + (size_t)(m0 + (tid>>3))*K + (tid&7)*8;
  const bf16_t* gb = B + (size_t)(n0 + (tid>>3))*K + (tid&7)*8;
  char* la = lA + tid*16;
  char* lb = lB + tid*16;

  f32x4 acc[4][4];
  #pragma unroll
  for (int a=0;a<4;a++)
    #pragma unroll
    for (int b=0;b<4;b++) acc[a][b] = (f32x4){0.f,0.f,0.f,0.f};

  for (int k0 = 0; k0 < K; k0 += 64) {
    __syncthreads();
    #pragma unroll
    for (int p=0;p<4;p++) {
      gload16(ga + (size_t)p*32*K + k0, la + p*4096);
      gload16(gb + (size_t)p*32*K + k0, lb + p*4096);
    }
    __syncthreads();   // compiler drains vmcnt before s_barrier
    #pragma unroll
    for (int t=0;t<2;t++) {
      bf16x8 af[4], bfr[4];
      #pragma unroll
      for (int mi=0;mi<4;mi++)
        af[mi] = *reinterpret_cast<const bf16x8*>(lA + (wr*64+mi*16+lr)*128 + t*64 + lg*16);
      #pragma unroll
      for (int ni=0;ni<4;ni++)
        bfr[ni] = *reinterpret_cast<const bf16x8*>(lB + (wc*64+ni*16+lr)*128 + t*64 + lg*16);
      #pragma unroll
      for (int mi=0;mi<4;mi++)
        #pragma unroll
        for (int ni=0;ni<4;ni++)
          acc[mi][ni] = __builtin_amdgcn_mfma_f32_16x16x32_bf16(af[mi], bfr[ni], acc[mi][ni], 0, 0, 0);
    }
  }

  if (!QKV || n0 < 2*D_MODEL) {
    #pragma unroll
    for (int mi=0;mi<4;mi++)
      #pragma unroll
      for (int ni=0;ni<4;ni++)
        #pragma unroll
        for (int r=0;r<4;r++) {
          int m = m0 + wr*64 + mi*16 + lg*4 + r;
          int n = n0 + wc*64 + ni*16 + lr;
          C[(size_t)m*N + n] = (OutT)acc[mi][ni][r];
        }
  } else {
    // V third: write transposed -> Vt[(b*16+h)*64 + d][s], row stride 2048
    #pragma unroll
    for (int mi=0;mi<4;mi++)
      #pragma unroll
      for (int ni=0;ni<4;ni++)
        #pragma unroll
        for (int r=0;r<4;r++) {
          int m = m0 + wr*64 + mi*16 + lg*4 + r;
          int nl = n0 + wc*64 + ni*16 + lr - 2*D_MODEL;  // 0..1023
          int h = nl >> 6, d = nl & 63;
          int bb = m >> 11, s = m & (SEQ-1);
          Vt[(((size_t)(bb*16 + h)*64 + d) << 11) + s] = (bf16_t)acc[mi][ni][r];
        }
  }
}

// ---------------- Flash causal attention ----------------
// grid (16, B*H): block bx handles q-tiles {bx, 31-bx} (33 tile-units each).
// block = 4 waves x 16 q-rows. K and V^T staged identically (vector swizzled).
__global__ __launch_bounds__(256) void attn_kernel(const bf16_t* __restrict__ QKV,
                                                   const bf16_t* __restrict__ Vt,
                                                   bf16_t* __restrict__ Of) {
  __shared__ __align__(16) char sK [64*128];     // [key][64 dims] swizzled
  __shared__ __align__(16) char sVt[64*128];     // [dim][64 keys] swizzled
  __shared__ __align__(16) char sP [4][16*128];  // per-wave P [qrow][64 keys]

  int bh = blockIdx.y;
  int b = bh >> 4, h = bh & 15;
  int tid = threadIdx.x, wid = tid>>6, lane = tid&63;
  int lr = lane&15, lg = lane>>4;

  const bf16_t* Kb = QKV + D_MODEL;                  // K columns
  const bf16_t* Vb = Vt + (size_t)bh*64*SEQ;         // this head's V^T [64][2048]

  for (int half = 0; half < 2; ++half) {
    int qt = half ? (31 - (int)blockIdx.x) : (int)blockIdx.x;
    int q0 = qt*64 + wid*16;

    bf16x8 qf[2];
    const bf16_t* qrow = QKV + (size_t)(b*SEQ + q0 + lr)*NQKV + h*64;
    qf[0] = *reinterpret_cast<const bf16x8*>(qrow + lg*8);
    qf[1] = *reinterpret_cast<const bf16x8*>(qrow + 32 + lg*8);

    f32x4 Oacc[4];
    #pragma unroll
    for (int ni=0;ni<4;ni++) Oacc[ni] = (f32x4){0.f,0.f,0.f,0.f};
    float mrun[4], lrun[4];
    #pragma unroll
    for (int r=0;r<4;r++) { mrun[r] = -__builtin_inff(); lrun[r] = 0.f; }

    for (int ti = 0; ti <= qt; ++ti) {
      int k0 = ti*64;
      __syncthreads();
      #pragma unroll
      for (int p2=0;p2<2;p2++) {
        int idx = p2*256 + tid;
        int row = idx>>3, c8 = (idx&7)*8;
        bf16x8 kv = *reinterpret_cast<const bf16x8*>(Kb + (size_t)(b*SEQ + k0 + row)*NQKV + h*64 + c8);
        *reinterpret_cast<bf16x8*>(sK + swz128(row, c8*2)) = kv;
        bf16x8 vv = *reinterpret_cast<const bf16x8*>(Vb + (size_t)row*SEQ + k0 + c8);
        *reinterpret_cast<bf16x8*>(sVt + swz128(row, c8*2)) = vv;
      }
      __syncthreads();

      // S = Q K^T (16 q x 64 keys per wave); scale*log2e pre-folded into Q
      f32x4 sfr[4];
      #pragma unroll
      for (int cb=0;cb<4;cb++) sfr[cb] = (f32x4){0.f,0.f,0.f,0.f};
      #pragma unroll
      for (int t=0;t<2;t++)
        #pragma unroll
        for (int cb=0;cb<4;cb++) {
          bf16x8 kfr = *reinterpret_cast<const bf16x8*>(sK + swz128(cb*16 + lr, t*64 + lg*16));
          sfr[cb] = __builtin_amdgcn_mfma_f32_16x16x32_bf16(qf[t], kfr, sfr[cb], 0, 0, 0);
        }

      bool diag = (ti == qt);   // mask only on the diagonal tile
      float pv[4][4];
      #pragma unroll
      for (int r=0;r<4;r++) {
        float rmax = -__builtin_inff();
        #pragma unroll
        for (int cb=0;cb<4;cb++) {
          float sv = sfr[cb][r];
          if (diag) sv = (k0 + cb*16 + lr <= q0 + lg*4 + r) ? sv : -__builtin_inff();
          pv[r][cb] = sv;
          rmax = fmaxf(rmax, sv);
        }
        #pragma unroll
        for (int m=1;m<16;m<<=1) rmax = fmaxf(rmax, __shfl_xor(rmax, m, 64));
        float mnew  = fmaxf(mrun[r], rmax);
        float alpha = exp2f(mrun[r] - mnew);
        mrun[r] = mnew;
        float rsum = 0.f;
        #pragma unroll
        for (int cb=0;cb<4;cb++) {
          float e = exp2f(pv[r][cb] - mnew);   // exp2(-inf)=0 handles mask
          pv[r][cb] = e;
          rsum += e;
        }
        #pragma unroll
        for (int m=1;m<16;m<<=1) rsum += __shfl_xor(rsum, m, 64);
        lrun[r] = lrun[r]*alpha + rsum;
        #pragma unroll
        for (int ni=0;ni<4;ni++) Oacc[ni][r] *= alpha;
        #pragma unroll
        for (int cb=0;cb<4;cb++)
          *reinterpret_cast<bf16_t*>(sP[wid] + swz128(lg*4 + r, (cb*16 + lr)*2)) = (bf16_t)pv[r][cb];
      }
      asm volatile("s_waitcnt lgkmcnt(0)" ::: "memory");
      __builtin_amdgcn_sched_barrier(0);

      // O += P V   (B-frags from V^T rows = dims)
      #pragma unroll
      for (int t=0;t<2;t++) {
        bf16x8 pf = *reinterpret_cast<const bf16x8*>(sP[wid] + swz128(lr, t*64 + lg*16));
        #pragma unroll
        for (int ni=0;ni<4;ni++) {
          bf16x8 vfr = *reinterpret_cast<const bf16x8*>(sVt + swz128(ni*16 + lr, t*64 + lg*16));
          Oacc[ni] = __builtin_amdgcn_mfma_f32_16x16x32_bf16(pf, vfr, Oacc[ni], 0, 0, 0);
        }
      }
    }

    #pragma unroll
    for (int ni=0;ni<4;ni++)
      #pragma unroll
      for (int r=0;r<4;r++) {
        int tok = b*SEQ + q0 + lg*4 + r;
        Of[(size_t)tok*D_MODEL + h*64 + ni*16 + lr] = (bf16_t)(Oacc[ni][r] / lrun[r]);
      }
  }
}

// ---------------- launch ----------------
extern "C" void kernel_launch(void* const* d_in, const int* in_sizes, int n_in,
                              void* d_out, int out_size, void* d_ws, size_t ws_size,
                              hipStream_t stream) {
  const float* x   = (const float*)d_in[0];
  const int*   pos = (const int*)  d_in[1];
  const float* wq  = (const float*)d_in[2];
  const float* wk  = (const float*)d_in[3];
  const float* wv  = (const float*)d_in[4];
  const float* wo  = (const float*)d_in[5];
  float* out = (float*)d_out;

  char* ws = (char*)d_ws;
  bf16_t* xb   = (bf16_t*)(ws);                 // 8 MB; reused as Of after QKV gemm
  bf16_t* wqkv = (bf16_t*)(ws + ( 8u<<20));     // 6 MB
  bf16_t* wob  = (bf16_t*)(ws + (14u<<20));     // 2 MB
  bf16_t* QKV  = (bf16_t*)(ws + (16u<<20));     // 24 MB
  bf16_t* Vtb  = (bf16_t*)(ws + (40u<<20));     // 8 MB  (total 48 MB)
  bf16_t* Of   = xb;

  cvt_x<<<NTOK*D_MODEL/1024, 256, 0, stream>>>(x, xb);
  cvt_w<<<4*D_MODEL*D_MODEL/1024, 256, 0, stream>>>(wq, wk, wv, wo, wqkv, wob);

  dim3 gqkv(NQKV/128, NTOK/128);   // (24, 32)
  gemm_bt<bf16_t, true><<<gqkv, 256, 0, stream>>>(xb, wqkv, QKV, Vtb, NTOK, NQKV, D_MODEL);

  rope_qk<<<NTOK*NUM_HEADS*32/256, 256, 0, stream>>>(QKV, pos);

  dim3 gattn(16, BATCH*NUM_HEADS);  // (16, 32) triangle-paired
  attn_kernel<<<gattn, 256, 0, stream>>>(QKV, Vtb, Of);

  dim3 gout(D_MODEL/128, NTOK/128); // (8, 32)
  gemm_bt<float, false><<<gout, 256, 0, stream>>>(Of, wob, out, nullptr, NTOK, D_MODEL, D_MODEL);
}